// Round 3
// baseline (179.220 us; speedup 1.0000x reference)
//
#include <hip/hip_runtime.h>

typedef _Float16 f16;
typedef _Float16 f16x4 __attribute__((ext_vector_type(4)));
typedef _Float16 f16x8 __attribute__((ext_vector_type(8)));
typedef float    f32x4 __attribute__((ext_vector_type(4)));

#define BATCH 65536
#define INDIM 512
#define MD    64
#define MSZ   100
#define NCAT  35
#define CKSZ  5
#define ODIM  512
#define N1    256   // X cols: [bq(64) | cq(64) | S_raw(100) | pad(28)]
#define K2    128   // GEMM2 K: base attn (100) zero-padded to 128
#define NSLOT (NCAT*CKSZ)  // 175
#define RBS   264   // rb stride (f16)
#define PAS   136   // pa stride (f16)

static __device__ __forceinline__ f32x4 mfma16(f16x4 a, f16x4 b, f32x4 c) {
  return __builtin_amdgcn_mfma_f32_16x16x16f16(a, b, c, 0, 0, 0);
}

// ---------------- prep: B1[256][512]+bias1, B2b[512][128], C2cat[175][512] --
__global__ __launch_bounds__(256) void k_prep(
    const float* __restrict__ Wb, const float* __restrict__ bb,
    const float* __restrict__ Wc, const float* __restrict__ bc,
    const float* __restrict__ keys, const float* __restrict__ bvals,
    const float* __restrict__ cvals, const float* __restrict__ Wo,
    f16* __restrict__ B1, float* __restrict__ bias1,
    f16* __restrict__ B2b, f16* __restrict__ C2cat) {
  int id = blockIdx.x * 256 + threadIdx.x;
  if (id < N1 * INDIM) {
    int k = id & (INDIM - 1);
    int n = id >> 9;
    float v = 0.f;
    if (n < 64) v = Wb[n * INDIM + k];
    else if (n < 128) v = Wc[(n - 64) * INDIM + k];
    else if (n < 128 + MSZ) {
      int m = n - 128;
      float s = 0.f;
      for (int d = 0; d < MD; d++) { float kv = keys[m * MD + d]; s += kv * kv; }
      float dn = fmaxf(sqrtf(s), 1e-8f);
      float a = 0.f;
      for (int d = 0; d < MD; d++) a += Wb[d * INDIM + k] * keys[m * MD + d];
      v = a / dn;
    }
    B1[n * INDIM + k] = (f16)v;
    if (k == 0) {
      float bv = 0.f;
      if (n < 64) bv = bb[n];
      else if (n < 128) bv = bc[n - 64];
      else if (n < 128 + MSZ) {
        int m = n - 128;
        float s = 0.f;
        for (int d = 0; d < MD; d++) { float kv = keys[m * MD + d]; s += kv * kv; }
        float dn = fmaxf(sqrtf(s), 1e-8f);
        float a = 0.f;
        for (int d = 0; d < MD; d++) a += bb[d] * keys[m * MD + d];
        bv = a / dn;
      }
      bias1[n] = bv;
    }
  } else if (id < N1 * INDIM + ODIM * K2) {
    int id2 = id - N1 * INDIM;
    int o = id2 >> 7, kk = id2 & (K2 - 1);
    float v = 0.f;
    if (kk < MSZ) {
      for (int d = 0; d < MD; d++) v += bvals[kk * MD + d] * Wo[o * 128 + d];
    }
    B2b[o * K2 + kk] = (f16)v;
  } else {
    int id3 = id - N1 * INDIM - ODIM * K2;
    if (id3 < NSLOT * ODIM) {
      int s = id3 >> 9, o = id3 & 511;
      float v = 0.f;
      for (int d = 0; d < MD; d++) v += cvals[s * MD + d] * Wo[o * 128 + 64 + d];
      C2cat[s * ODIM + o] = (f16)v;
    }
  }
}

// ---------------- fused: GEMM1 -> softmax/mid (LDS) -> GEMM2+cat-gather ----
__global__ __launch_bounds__(256, 2) void k_fused(
    const float* __restrict__ q, const f16* __restrict__ B1,
    const float* __restrict__ bias1, const int* __restrict__ cidx,
    const float* __restrict__ catk, const f16* __restrict__ B2b,
    const f16* __restrict__ C2cat, const float* __restrict__ bout,
    float* __restrict__ out) {
  __shared__ f16 Al[64][40];       // phase1 A staging (write-then-read per iter)
  __shared__ f16 Bl[256][40];      // phase1/phase3 B staging (barrier-guarded)
  __shared__ f16 rb[64][RBS];      // X rows: written once (p1 epi), read once (p2)
  __shared__ f16 pa[64][PAS];      // A2-base: written once (p2), read (p3)
  __shared__ float cw[64][8];      // category weights
  __shared__ int   cs[64];         // category slot base

  const int tid = threadIdx.x;
  const int lane = tid & 63, wid = tid >> 6;      // 4 waves
  const int l15 = lane & 15, l4 = lane >> 4;
  const int row0 = blockIdx.x * 64;

  f32x4 acc[4][4];
#pragma unroll
  for (int i = 0; i < 4; i++)
#pragma unroll
    for (int j = 0; j < 4; j++) acc[i][j] = (f32x4){0.f, 0.f, 0.f, 0.f};

  // ===== phase 1: X = q @ B1^T + bias1 -> rb cols 0..255 =====
  const int arow = tid >> 2, aseg = tid & 3;
  for (int k0 = 0; k0 < INDIM; k0 += 32) {
    const float* qp = q + (size_t)(row0 + arow) * INDIM + k0 + aseg * 8;
    f32x4 a0 = *(const f32x4*)qp;
    f32x4 a1 = *(const f32x4*)(qp + 4);
    const f16* bp = B1 + (size_t)tid * INDIM + k0;
    f16x8 b0 = *(const f16x8*)(bp);
    f16x8 b1 = *(const f16x8*)(bp + 8);
    f16x8 b2 = *(const f16x8*)(bp + 16);
    f16x8 b3 = *(const f16x8*)(bp + 24);
    f16x8 av;
#pragma unroll
    for (int i = 0; i < 4; i++) { av[i] = (f16)a0[i]; av[4 + i] = (f16)a1[i]; }
    __syncthreads();
    *(f16x8*)&Al[arow][aseg * 8] = av;
    *(f16x8*)&Bl[tid][0]  = b0;
    *(f16x8*)&Bl[tid][8]  = b1;
    *(f16x8*)&Bl[tid][16] = b2;
    *(f16x8*)&Bl[tid][24] = b3;
    __syncthreads();
#pragma unroll
    for (int kk = 0; kk < 2; kk++) {
      const int kc = kk * 16 + 4 * l4;
      f16x4 af[4], bf[4];
#pragma unroll
      for (int mi = 0; mi < 4; mi++) af[mi] = *(const f16x4*)&Al[mi * 16 + l15][kc];
#pragma unroll
      for (int ni = 0; ni < 4; ni++) bf[ni] = *(const f16x4*)&Bl[wid * 64 + ni * 16 + l15][kc];
#pragma unroll
      for (int mi = 0; mi < 4; mi++)
#pragma unroll
        for (int ni = 0; ni < 4; ni++)
          acc[mi][ni] = mfma16(af[mi], bf[ni], acc[mi][ni]);
    }
  }
  // epilogue -> rb (this wave's 64 columns, all 64 rows)
#pragma unroll
  for (int ni = 0; ni < 4; ni++) {
    const int col = wid * 64 + ni * 16 + l15;
    const float bs = bias1[col];
#pragma unroll
    for (int mi = 0; mi < 4; mi++) {
      const int r = mi * 16 + 4 * l4;
#pragma unroll
      for (int j = 0; j < 4; j++)
        rb[r + j][col] = (f16)(acc[mi][ni][j] + bs);
    }
  }
  __syncthreads();

  // ===== phase 2: softmaxes; rb(read-only) -> pa / cw / cs =====
  for (int r2 = 0; r2 < 16; r2++) {
    const int row = wid * 16 + r2;
    float bq = (float)rb[row][lane];
    float cq = (float)rb[row][64 + lane];
    float s0 = (float)rb[row][128 + lane];
    float s1 = (lane < MSZ - 64) ? (float)rb[row][192 + lane] : 0.f;
    float nb = bq * bq;
#pragma unroll
    for (int o = 32; o; o >>= 1) nb += __shfl_xor(nb, o, 64);
    const float rinv = 1.f / fmaxf(sqrtf(nb), 1e-8f);
    float v0 = s0 * rinv;
    float v1 = (lane < MSZ - 64) ? s1 * rinv : -1e30f;
    float mx = fmaxf(v0, v1);
#pragma unroll
    for (int o = 32; o; o >>= 1) mx = fmaxf(mx, __shfl_xor(mx, o, 64));
    float e0 = __expf(v0 - mx);
    float e1 = (lane < MSZ - 64) ? __expf(v1 - mx) : 0.f;
    float es = e0 + e1;
#pragma unroll
    for (int o = 32; o; o >>= 1) es += __shfl_xor(es, o, 64);
    const float isum = 1.f / es;
    const float a0v = e0 * isum, a1v = e1 * isum;

    const int ci = cidx[row0 + row];
    const float* kp = catk + (size_t)ci * (CKSZ * MD);
    float t0 = cq * kp[0 * MD + lane];
    float t1 = cq * kp[1 * MD + lane];
    float t2 = cq * kp[2 * MD + lane];
    float t3 = cq * kp[3 * MD + lane];
    float t4 = cq * kp[4 * MD + lane];
#pragma unroll
    for (int o = 32; o; o >>= 1) {
      t0 += __shfl_xor(t0, o, 64); t1 += __shfl_xor(t1, o, 64);
      t2 += __shfl_xor(t2, o, 64); t3 += __shfl_xor(t3, o, 64);
      t4 += __shfl_xor(t4, o, 64);
    }
    float m5 = fmaxf(fmaxf(fmaxf(t0, t1), fmaxf(t2, t3)), t4);
    float ce0 = __expf(t0 - m5), ce1 = __expf(t1 - m5), ce2 = __expf(t2 - m5),
          ce3 = __expf(t3 - m5), ce4 = __expf(t4 - m5);
    const float ics = 1.f / (ce0 + ce1 + ce2 + ce3 + ce4);

    pa[row][lane]      = (f16)a0v;
    pa[row][64 + lane] = (lane < MSZ - 64) ? (f16)a1v : (f16)0.0f;  // zero pad 100..127
    if (lane < CKSZ) {
      float cev = (lane == 0) ? ce0 : (lane == 1) ? ce1 : (lane == 2) ? ce2
                : (lane == 3) ? ce3 : ce4;
      cw[row][lane] = cev * ics;
    }
    if (lane == 0) cs[row] = ci * CKSZ;
  }
  __syncthreads();

  // ===== phase 3: out = pa @ B2b^T + bout + rank-5 cat gather =====
  for (int cpass = 0; cpass < 2; cpass++) {
    const int col0 = cpass * 256;
#pragma unroll
    for (int i = 0; i < 4; i++)
#pragma unroll
      for (int j = 0; j < 4; j++) acc[i][j] = (f32x4){0.f, 0.f, 0.f, 0.f};
    for (int k0 = 0; k0 < K2; k0 += 32) {
      const f16* bp2 = B2b + (size_t)(col0 + tid) * K2 + k0;
      f16x8 c0 = *(const f16x8*)(bp2);
      f16x8 c1 = *(const f16x8*)(bp2 + 8);
      f16x8 c2 = *(const f16x8*)(bp2 + 16);
      f16x8 c3 = *(const f16x8*)(bp2 + 24);
      __syncthreads();
      *(f16x8*)&Bl[tid][0]  = c0;
      *(f16x8*)&Bl[tid][8]  = c1;
      *(f16x8*)&Bl[tid][16] = c2;
      *(f16x8*)&Bl[tid][24] = c3;
      __syncthreads();
#pragma unroll
      for (int kk = 0; kk < 2; kk++) {
        const int kc = kk * 16 + 4 * l4;
        f16x4 af[4], bf[4];
#pragma unroll
        for (int mi = 0; mi < 4; mi++) af[mi] = *(const f16x4*)&pa[mi * 16 + l15][k0 + kc];
#pragma unroll
        for (int ni = 0; ni < 4; ni++) bf[ni] = *(const f16x4*)&Bl[wid * 64 + ni * 16 + l15][kc];
#pragma unroll
        for (int mi = 0; mi < 4; mi++)
#pragma unroll
          for (int ni = 0; ni < 4; ni++)
            acc[mi][ni] = mfma16(af[mi], bf[ni], acc[mi][ni]);
      }
    }
    // epilogue: bias + rank-5 category gather + store
    float bs[4];
#pragma unroll
    for (int ni = 0; ni < 4; ni++) bs[ni] = bout[col0 + wid * 64 + ni * 16 + l15];
#pragma unroll
    for (int mi = 0; mi < 4; mi++) {
#pragma unroll
      for (int j = 0; j < 4; j++) {
        const int r = mi * 16 + 4 * l4 + j;
        const int cb = cs[r];
        const float w0 = cw[r][0], w1 = cw[r][1], w2 = cw[r][2],
                    w3 = cw[r][3], w4 = cw[r][4];
        const f16* cp = C2cat + (size_t)cb * ODIM + col0 + wid * 64 + l15;
#pragma unroll
        for (int ni = 0; ni < 4; ni++) {
          const int col = col0 + wid * 64 + ni * 16 + l15;
          const f16* cpn = cp + ni * 16;
          float v = acc[mi][ni][j] + bs[ni];
          v += w0 * (float)cpn[0]
             + w1 * (float)cpn[ODIM]
             + w2 * (float)cpn[2 * ODIM]
             + w3 * (float)cpn[3 * ODIM]
             + w4 * (float)cpn[4 * ODIM];
          out[(size_t)(row0 + r) * ODIM + col] = v;
        }
      }
    }
  }
}

extern "C" void kernel_launch(void* const* d_in, const int* in_sizes, int n_in,
                              void* d_out, int out_size, void* d_ws, size_t ws_size,
                              hipStream_t stream) {
  const float* query = (const float*)d_in[0];
  const int*   cidx  = (const int*)d_in[1];
  const float* Wb    = (const float*)d_in[2];
  const float* bb    = (const float*)d_in[3];
  const float* Wc    = (const float*)d_in[4];
  const float* bc    = (const float*)d_in[5];
  const float* bkeys = (const float*)d_in[6];
  const float* bvals = (const float*)d_in[7];
  const float* ckeys = (const float*)d_in[8];
  const float* cvals = (const float*)d_in[9];
  const float* Wo    = (const float*)d_in[10];
  const float* bo    = (const float*)d_in[11];
  float* out = (float*)d_out;

  char* ws = (char*)d_ws;
  f16*   B1    = (f16*)(ws);                       // 256*512*2   = 262144
  f16*   B2b   = (f16*)(ws + 262144);              // 512*128*2   = 131072
  f16*   C2cat = (f16*)(ws + 262144 + 131072);     // 175*512*2   = 179200
  float* bias1 = (float*)(ws + 262144 + 131072 + 179200);  // 1024

  const int prep_ids = N1 * INDIM + ODIM * K2 + NSLOT * ODIM;  // 286208
  k_prep<<<dim3((prep_ids + 255) / 256), 256, 0, stream>>>(
      Wb, bb, Wc, bc, bkeys, bvals, cvals, Wo, B1, bias1, B2b, C2cat);
  k_fused<<<dim3(BATCH / 64), 256, 0, stream>>>(
      query, B1, bias1, cidx, ckeys, B2b, C2cat, bo, out);
}